// Round 1
// baseline (2006.681 us; speedup 1.0000x reference)
//
#include <hip/hip_runtime.h>
#include <stdint.h>

#define T_LEN 4096
#define NHID  128

typedef float    f32x4 __attribute__((ext_vector_type(4)));
typedef _Float16 f16x4 __attribute__((ext_vector_type(4)));
typedef _Float16 f16x8 __attribute__((ext_vector_type(8)));
typedef __fp16   h16x2 __attribute__((ext_vector_type(2)));
typedef uint32_t u32x2 __attribute__((ext_vector_type(2)));
typedef uint32_t u32x4 __attribute__((ext_vector_type(4)));

struct P2 { h16x2 p0, p1; };
struct P4 { h16x2 p0, p1, p2, p3; };
struct U22 { u32x2 a, b; };

static __device__ __forceinline__ f16x4 cvt_f16x4(f32x4 v) {
    P2 p;
    p.p0 = __builtin_amdgcn_cvt_pkrtz(v.x, v.y);
    p.p1 = __builtin_amdgcn_cvt_pkrtz(v.z, v.w);
    return __builtin_bit_cast(f16x4, p);
}
static __device__ __forceinline__ f16x8 cvt_f16x8(f32x4 a, f32x4 b) {
    P4 p;
    p.p0 = __builtin_amdgcn_cvt_pkrtz(a.x, a.y);
    p.p1 = __builtin_amdgcn_cvt_pkrtz(a.z, a.w);
    p.p2 = __builtin_amdgcn_cvt_pkrtz(b.x, b.y);
    p.p3 = __builtin_amdgcn_cvt_pkrtz(b.z, b.w);
    return __builtin_bit_cast(f16x8, p);
}
static __device__ __forceinline__ f32x4 relu4(f32x4 v) {
    v.x = fmaxf(v.x, 0.f); v.y = fmaxf(v.y, 0.f);
    v.z = fmaxf(v.z, 0.f); v.w = fmaxf(v.w, 0.f);
    return v;
}
// pack f32x4 -> 4 f16 (RTZ) then relu in f16 (identical result to relu-then-pack)
static __device__ __forceinline__ u32x2 relu_pk(f32x4 v) {
    P2 p;
    p.p0 = __builtin_amdgcn_cvt_pkrtz(v.x, v.y);
    p.p1 = __builtin_amdgcn_cvt_pkrtz(v.z, v.w);
    f16x4 h = __builtin_bit_cast(f16x4, p);
    const f16x4 z = {};
    h = __builtin_elementwise_max(h, z);   // 2x v_pk_max_f16
    return __builtin_bit_cast(u32x2, h);
}
#define MFMA32(a, b, c) __builtin_amdgcn_mfma_f32_16x16x32_f16((a), (b), (c), 0, 0, 0)
#define MFMA16(a, b, c) __builtin_amdgcn_mfma_f32_16x16x16f16((a), (b), (c), 0, 0, 0)

// Layouts (per batch group g = blockIdx of rec; lane l=(u<<4)|c, batch=16g+c):
//   phiC (C-frag / h storage): unit(m,u,i) = 16m + 4u + i        (m=0..7, i=0..3)
//   phiB (W1h K-axis gather):  unit(kt,u,j) = 64*(j>>2) + 16kt + 4u + (j&3)
// Under these, B-frag[kt] of step t+1 == concat(pk[kt], pk[kt+4]) of step t's
// packed C output — the recurrence needs NO cross-lane movement at all.
//
// xp (f32, phiC layout, in d_out):  xp[ ((g*T + t)*8 + m)*256 + 4l + i ]
// hg (packed f16, in d_ws):         hg[ (g*T + t)*1024 + q*256 + 4l + {0..3} ]
//                                   (q-th u32x4 = {pk[2q], pk[2q+1]})

// -------------------------------------------------------------------------
// Kernel 0: xp = input . W1x^T + b1  (K=32 MFMA), f32 accum stored verbatim.
// Grid 1024 = g*256 + tc, block 64, 16 t per block.
// -------------------------------------------------------------------------
__global__ __launch_bounds__(64, 2)
void xproj_kernel(const float* __restrict__ input, const float* __restrict__ W1,
                  const float* __restrict__ b1, float* __restrict__ xp) {
    const int bid = blockIdx.x;
    const int g   = bid >> 8;          // 0..3
    const int tc  = bid & 255;         // 0..255
    const int l   = threadIdx.x;
    const int c   = l & 15, u = l >> 4;

    // A-fragments of W1x (cols 128..255): A[m=c][k=32j+8u+0..7]
    f16x8 wa[8][4];
#pragma unroll
    for (int m = 0; m < 8; ++m) {
        const float* wr = W1 + (16 * m + c) * 256 + 128 + 8 * u;
#pragma unroll
        for (int j = 0; j < 4; ++j)
            wa[m][j] = cvt_f16x8(*(const f32x4*)(wr + 32 * j),
                                 *(const f32x4*)(wr + 32 * j + 4));
    }
    f32x4 bi[8];
#pragma unroll
    for (int m = 0; m < 8; ++m) bi[m] = *(const f32x4*)(b1 + 16 * m + 4 * u);

    const int t0 = tc * 16;
    const float* ip0 = input + (size_t)(16 * g + c) * T_LEN * NHID + 8 * u;
    float* xp0 = xp + ((size_t)g * T_LEN) * 2048 + 4 * l;
#pragma unroll 1
    for (int tt = 0; tt < 16; ++tt) {
        const int t = t0 + tt;
        const float* ip = ip0 + (size_t)t * NHID;
        f16x8 xb[4];
#pragma unroll
        for (int j = 0; j < 4; ++j)
            xb[j] = cvt_f16x8(*(const f32x4*)(ip + 32 * j),
                              *(const f32x4*)(ip + 32 * j + 4));
        float* xpt = xp0 + (size_t)t * 2048;
#pragma unroll
        for (int m = 0; m < 8; ++m) {
            f32x4 a = bi[m];
#pragma unroll
            for (int j = 0; j < 4; ++j) a = MFMA32(wa[m][j], xb[j], a);
            *(f32x4*)(xpt + m * 256) = a;
        }
    }
}

// -------------------------------------------------------------------------
// Kernel 1: recurrence. Grid 4 (g), block 64 = ONE wave. h lives in registers;
// zero LDS, zero barriers, zero shuffles (phiB relabeling makes C-frags == next
// step's B-frags). 32x mfma_16x16x32_f16 per step; xp prefetch ring depth 4.
// -------------------------------------------------------------------------
__global__ __launch_bounds__(64, 1)
void rec_kernel(const float* __restrict__ xp, const float* __restrict__ W1,
                uint32_t* __restrict__ hg) {
    const int g = blockIdx.x;
    const int l = threadIdx.x;
    const int c = l & 15, u = l >> 4;

    // W1h A-frags, K-axis permuted by phiB:
    //   waH[m][kt] element j = W1h[16m+c][ 64*(j>>2) + 16kt + 4u + (j&3) ]
    // = two strided f32x4 loads per fragment.
    f16x8 waH[8][4];
#pragma unroll
    for (int m = 0; m < 8; ++m) {
        const float* wr = W1 + (16 * m + c) * 256;   // h-part: cols 0..127
#pragma unroll
        for (int kt = 0; kt < 4; ++kt)
            waH[m][kt] = cvt_f16x8(*(const f32x4*)(wr + 16 * kt + 4 * u),
                                   *(const f32x4*)(wr + 64 + 16 * kt + 4 * u));
    }

    const float* xpg = xp + ((size_t)g * T_LEN) * 2048 + 4 * l;
    uint32_t*    hgp = hg + ((size_t)g * T_LEN) * 1024 + 4 * l;

    // h_0 = 0
    f16x8 bf[4];
#pragma unroll
    for (int kt = 0; kt < 4; ++kt) {
        const u32x4 z = {0, 0, 0, 0};
        bf[kt] = __builtin_bit_cast(f16x8, z);
    }

    // xp prefetch ring, depth 4 (f32, feeds MFMA C-init directly)
    f32x4 xb[4][8];
#pragma unroll
    for (int p = 0; p < 4; ++p)
#pragma unroll
        for (int m = 0; m < 8; ++m)
            xb[p][m] = *(const f32x4*)(xpg + (size_t)p * 2048 + m * 256);

    u32x2 pk[8];

#pragma unroll 1
    for (int t4 = 0; t4 < T_LEN; t4 += 4) {
#pragma unroll
        for (int p = 0; p < 4; ++p) {
            const int t = t4 + p;
            f32x4 acc[8];
#pragma unroll
            for (int m = 0; m < 8; ++m) acc[m] = xb[p][m];
            // m interleave 0,4,1,5,2,6,3,7: acc[0],acc[4] (-> bf[0]) retire
            // earliest in the last kt round, shrinking the inter-step bubble.
#pragma unroll
            for (int kt = 0; kt < 4; ++kt) {
#pragma unroll
                for (int i = 0; i < 8; ++i) {
                    const int m = ((i & 1) << 2) | (i >> 1);
                    acc[m] = MFMA32(waH[m][kt], bf[kt], acc[m]);
                }
            }
            // pack h_{t+1}; B-frags for step t+2 are pure register concats
#pragma unroll
            for (int kk = 0; kk < 4; ++kk) {
                pk[kk]     = relu_pk(acc[kk]);
                pk[kk + 4] = relu_pk(acc[kk + 4]);
                U22 qq = { pk[kk], pk[kk + 4] };
                bf[kk] = __builtin_bit_cast(f16x8, qq);
            }
            // stream h_{t+1} to HBM for out_kernel (fire-and-forget)
            uint32_t* hp = hgp + (size_t)t * 1024;
#pragma unroll
            for (int q = 0; q < 4; ++q) {
                U22 qq = { pk[2 * q], pk[2 * q + 1] };
                *(u32x4*)(hp + q * 256) = __builtin_bit_cast(u32x4, qq);
            }
            // prefetch xp for t+4 (clamped tail; dummies unused)
            int tn = t + 4; if (tn > T_LEN - 1) tn = T_LEN - 1;
            const float* xpt = xpg + (size_t)tn * 2048;
#pragma unroll
            for (int m = 0; m < 8; ++m) xb[p][m] = *(const f32x4*)(xpt + m * 256);
        }
    }
}

// -------------------------------------------------------------------------
// Kernel 2: out[b,t,:] = relu(W2 . h_{t+1} + b2), K=16 MFMA.
// h fragments read verbatim (C-frag == B-frag for 16x16x16 under phiC).
// Grid 2048 = g*512 + tc, block 64, 8 t per block.
// -------------------------------------------------------------------------
__global__ __launch_bounds__(64, 2)
void out_kernel(const uint32_t* __restrict__ hg, const float* __restrict__ W2,
                const float* __restrict__ b2, float* __restrict__ out) {
    const int bid = blockIdx.x;
    const int g   = bid >> 9;
    const int tc  = bid & 511;
    const int l   = threadIdx.x;
    const int c   = l & 15, u = l >> 4;

    f16x4 wa[8][8];
#pragma unroll
    for (int m = 0; m < 8; ++m) {
        const float* wr = W2 + (16 * m + c) * 128 + 4 * u;
#pragma unroll
        for (int s = 0; s < 8; ++s)
            wa[m][s] = cvt_f16x4(*(const f32x4*)(wr + 16 * s));
    }
    f32x4 bi[8];
#pragma unroll
    for (int m = 0; m < 8; ++m) bi[m] = *(const f32x4*)(b2 + 16 * m + 4 * u);

    const int t0 = tc * 8;
    const uint32_t* hg0 = hg + ((size_t)g * T_LEN) * 1024 + 4 * l;
    float* op0 = out + (size_t)(16 * g + c) * T_LEN * NHID + 4 * u;
#pragma unroll 1
    for (int tt = 0; tt < 8; ++tt) {
        const int t = t0 + tt;
        const uint32_t* hp = hg0 + (size_t)t * 1024;
        f16x4 hb[8];
#pragma unroll
        for (int s = 0; s < 8; ++s)
            hb[s] = __builtin_bit_cast(f16x4,
                        *(const u32x2*)(hp + (s >> 1) * 256 + (s & 1) * 2));
        f32x4 acc[8];
#pragma unroll
        for (int m = 0; m < 8; ++m) {
            f32x4 a = bi[m];
#pragma unroll
            for (int s = 0; s < 8; ++s) a = MFMA16(wa[m][s], hb[s], a);
            acc[m] = relu4(a);
        }
        float* op = op0 + (size_t)t * NHID;
#pragma unroll
        for (int m = 0; m < 8; ++m) *(f32x4*)(op + 16 * m) = acc[m];
    }
}

// -------------------------------------------------------------------------
extern "C" void kernel_launch(void* const* d_in, const int* in_sizes, int n_in,
                              void* d_out, int out_size, void* d_ws, size_t ws_size,
                              hipStream_t stream) {
    const float* input = (const float*)d_in[0];  // (64, 4096, 128) f32
    const float* W1    = (const float*)d_in[1];  // (128, 256) f32
    const float* b1    = (const float*)d_in[2];  // (128,) f32
    const float* W2    = (const float*)d_in[3];  // (128, 128) f32
    const float* b2    = (const float*)d_in[4];  // (128,) f32
    float*    out = (float*)d_out;
    float*    xpb = (float*)d_out;               // xp scratch: full 128 MiB of
                                                 // d_out (f32), fully consumed
                                                 // by rec before out_kernel
                                                 // overwrites it
    uint32_t* hgb = (uint32_t*)d_ws;             // h stream: 64 MiB in d_ws

    xproj_kernel<<<1024, 64, 0, stream>>>(input, W1, b1, xpb);
    rec_kernel  <<<4,    64, 0, stream>>>(xpb, W1, hgb);
    out_kernel  <<<2048, 64, 0, stream>>>(hgb, W2, b2, out);
}

// Round 2
// 1969.621 us; speedup vs baseline: 1.0188x; 1.0188x over previous
//
#include <hip/hip_runtime.h>
#include <stdint.h>

#define T_LEN 4096
#define NHID  128

typedef float    f32x4 __attribute__((ext_vector_type(4)));
typedef _Float16 f16x4 __attribute__((ext_vector_type(4)));
typedef _Float16 f16x8 __attribute__((ext_vector_type(8)));
typedef __fp16   h16x2 __attribute__((ext_vector_type(2)));
typedef uint32_t u32x2 __attribute__((ext_vector_type(2)));
typedef uint32_t u32x4 __attribute__((ext_vector_type(4)));

struct P2 { h16x2 p0, p1; };
struct P4 { h16x2 p0, p1, p2, p3; };
struct U22 { u32x2 a, b; };

static __device__ __forceinline__ f16x4 cvt_f16x4(f32x4 v) {
    P2 p;
    p.p0 = __builtin_amdgcn_cvt_pkrtz(v.x, v.y);
    p.p1 = __builtin_amdgcn_cvt_pkrtz(v.z, v.w);
    return __builtin_bit_cast(f16x4, p);
}
static __device__ __forceinline__ f16x8 cvt_f16x8(f32x4 a, f32x4 b) {
    P4 p;
    p.p0 = __builtin_amdgcn_cvt_pkrtz(a.x, a.y);
    p.p1 = __builtin_amdgcn_cvt_pkrtz(a.z, a.w);
    p.p2 = __builtin_amdgcn_cvt_pkrtz(b.x, b.y);
    p.p3 = __builtin_amdgcn_cvt_pkrtz(b.z, b.w);
    return __builtin_bit_cast(f16x8, p);
}
static __device__ __forceinline__ f32x4 relu4(f32x4 v) {
    v.x = fmaxf(v.x, 0.f); v.y = fmaxf(v.y, 0.f);
    v.z = fmaxf(v.z, 0.f); v.w = fmaxf(v.w, 0.f);
    return v;
}
// pack f32x4 -> 4 f16 (RTZ) then relu in f16 (identical result to relu-then-pack)
static __device__ __forceinline__ u32x2 relu_pk(f32x4 v) {
    P2 p;
    p.p0 = __builtin_amdgcn_cvt_pkrtz(v.x, v.y);
    p.p1 = __builtin_amdgcn_cvt_pkrtz(v.z, v.w);
    f16x4 h = __builtin_bit_cast(f16x4, p);
    const f16x4 z = {};
    h = __builtin_elementwise_max(h, z);   // 2x v_pk_max_f16
    return __builtin_bit_cast(u32x2, h);
}
#define MFMA32(a, b, c) __builtin_amdgcn_mfma_f32_16x16x32_f16((a), (b), (c), 0, 0, 0)
#define MFMA16(a, b, c) __builtin_amdgcn_mfma_f32_16x16x16f16((a), (b), (c), 0, 0, 0)

// LDS-only barrier: drains LDS ops, leaves global (vmcnt) traffic in flight.
// NEVER __syncthreads() here - it waits vmcnt(0) and would re-introduce the
// store/load drain this design exists to remove.
#define LDS_BARRIER() asm volatile("s_waitcnt lgkmcnt(0)\n\ts_barrier" ::: "memory")

// Layouts (per batch group g = blockIdx of rec; lane l=(u<<4)|c, batch=16g+c):
//   phiC (C-frag / h storage): unit(m,u,i) = 16m + 4u + i        (m=0..7, i=0..3)
//   phiB (W1h K-axis gather):  unit(kt,u,j) = 64*(j>>2) + 16kt + 4u + (j&3)
// Under these, B-frag[kt] of step t+1 == concat(pk[kt], pk[kt+4]) of step t's
// packed C output — the recurrence needs NO cross-lane movement at all.
//
// xp (f32, phiC layout, in d_out):  xp[ ((g*T + t)*8 + m)*256 + 4l + i ]
// hg (packed f16, in d_ws):         hg[ (g*T + t)*1024 + q*256 + 4l + {0..3} ]
//                                   (q-th u32x4 = {pk[2q], pk[2q+1]})

// -------------------------------------------------------------------------
// Kernel 0: xp = input . W1x^T + b1  (K=32 MFMA), f32 accum stored verbatim.
// Grid 1024 = g*256 + tc, block 64, 16 t per block.
// -------------------------------------------------------------------------
__global__ __launch_bounds__(64, 2)
void xproj_kernel(const float* __restrict__ input, const float* __restrict__ W1,
                  const float* __restrict__ b1, float* __restrict__ xp) {
    const int bid = blockIdx.x;
    const int g   = bid >> 8;          // 0..3
    const int tc  = bid & 255;         // 0..255
    const int l   = threadIdx.x;
    const int c   = l & 15, u = l >> 4;

    // A-fragments of W1x (cols 128..255): A[m=c][k=32j+8u+0..7]
    f16x8 wa[8][4];
#pragma unroll
    for (int m = 0; m < 8; ++m) {
        const float* wr = W1 + (16 * m + c) * 256 + 128 + 8 * u;
#pragma unroll
        for (int j = 0; j < 4; ++j)
            wa[m][j] = cvt_f16x8(*(const f32x4*)(wr + 32 * j),
                                 *(const f32x4*)(wr + 32 * j + 4));
    }
    f32x4 bi[8];
#pragma unroll
    for (int m = 0; m < 8; ++m) bi[m] = *(const f32x4*)(b1 + 16 * m + 4 * u);

    const int t0 = tc * 16;
    const float* ip0 = input + (size_t)(16 * g + c) * T_LEN * NHID + 8 * u;
    float* xp0 = xp + ((size_t)g * T_LEN) * 2048 + 4 * l;
#pragma unroll 1
    for (int tt = 0; tt < 16; ++tt) {
        const int t = t0 + tt;
        const float* ip = ip0 + (size_t)t * NHID;
        f16x8 xb[4];
#pragma unroll
        for (int j = 0; j < 4; ++j)
            xb[j] = cvt_f16x8(*(const f32x4*)(ip + 32 * j),
                              *(const f32x4*)(ip + 32 * j + 4));
        float* xpt = xp0 + (size_t)t * 2048;
#pragma unroll
        for (int m = 0; m < 8; ++m) {
            f32x4 a = bi[m];
#pragma unroll
            for (int j = 0; j < 4; ++j) a = MFMA32(wa[m][j], xb[j], a);
            *(f32x4*)(xpt + m * 256) = a;
        }
    }
}

// -------------------------------------------------------------------------
// Kernel 1: recurrence. Grid 4 (g), block 128 = 2 waves, producer/consumer.
//   Wave 0 (compute): h register-resident, 32 MFMA/step, depth-4 xp load
//     ring, ZERO global stores (so its vmcnt waits are only the xb RAW at
//     distance 4 steps -> full load concurrency). h goes to a 32 KB LDS
//     double buffer (chunk = 4 steps), conflict-free b128 pattern.
//   Wave 1 (drainer): per chunk, LDS -> HBM stores of the previous chunk.
//     All store-retire latency and store-data WAR waits land on this wave,
//     which has ~4x slack.
// One LDS-only barrier per 4 steps. Divergent-branch barriers are legal:
// both waves execute exactly T_LEN/4 barriers.
// -------------------------------------------------------------------------
__global__ __launch_bounds__(128, 1)
void rec_kernel(const float* __restrict__ xp, const float* __restrict__ W1,
                uint32_t* __restrict__ hg) {
    const int g = blockIdx.x;
    const int w = threadIdx.x >> 6;
    const int l = threadIdx.x & 63;
    const int c = l & 15, u = l >> 4;

    // [slot][sp][q][4l+i] : ((slot*4+sp)*4+q)*256 + 4l  (2 slots x 4 KB/step)
    __shared__ uint32_t hring[2 * 4 * 4 * 256];   // 32 KB

    if (w == 0) {
        // ---- compute wave ----
        // W1h A-frags, K-axis permuted by phiB:
        //   waH[m][kt] element j = W1h[16m+c][ 64*(j>>2) + 16kt + 4u + (j&3) ]
        f16x8 waH[8][4];
#pragma unroll
        for (int m = 0; m < 8; ++m) {
            const float* wr = W1 + (16 * m + c) * 256;   // h-part: cols 0..127
#pragma unroll
            for (int kt = 0; kt < 4; ++kt)
                waH[m][kt] = cvt_f16x8(*(const f32x4*)(wr + 16 * kt + 4 * u),
                                       *(const f32x4*)(wr + 64 + 16 * kt + 4 * u));
        }

        const float* xpg = xp + ((size_t)g * T_LEN) * 2048 + 4 * l;

        // h_0 = 0
        f16x8 bf[4];
#pragma unroll
        for (int kt = 0; kt < 4; ++kt) {
            const u32x4 z = {0, 0, 0, 0};
            bf[kt] = __builtin_bit_cast(f16x8, z);
        }

        // xp prefetch ring, depth 4 (f32, feeds MFMA C-init directly)
        f32x4 xb[4][8];
#pragma unroll
        for (int p = 0; p < 4; ++p)
#pragma unroll
            for (int m = 0; m < 8; ++m)
                xb[p][m] = *(const f32x4*)(xpg + (size_t)p * 2048 + m * 256);

#pragma unroll 1
        for (int t4 = 0; t4 < T_LEN; t4 += 4) {
            uint32_t* hl = &hring[((t4 >> 2) & 1) * 4096];
#pragma unroll
            for (int p = 0; p < 4; ++p) {
                const int t = t4 + p;
                f32x4 acc[8];
#pragma unroll
                for (int m = 0; m < 8; ++m) acc[m] = xb[p][m];
                // m interleave 0,4,1,5,...: acc[0],acc[4] (-> bf[0]) retire
                // earliest in the last kt round.
#pragma unroll
                for (int kt = 0; kt < 4; ++kt) {
#pragma unroll
                    for (int i = 0; i < 8; ++i) {
                        const int m = ((i & 1) << 2) | (i >> 1);
                        acc[m] = MFMA32(waH[m][kt], bf[kt], acc[m]);
                    }
                }
                // pack h_{t+1}; B-frags for step t+2 are register concats
                u32x2 pk[8];
#pragma unroll
                for (int kk = 0; kk < 4; ++kk) {
                    pk[kk]     = relu_pk(acc[kk]);
                    pk[kk + 4] = relu_pk(acc[kk + 4]);
                    U22 qq = { pk[kk], pk[kk + 4] };
                    bf[kk] = __builtin_bit_cast(f16x8, qq);
                }
                // h_{t+1} -> LDS (wave 1 streams it to HBM). ds_write WAR on
                // pk is lgkm-scoped (~30 cyc) - harmless.
#pragma unroll
                for (int q = 0; q < 4; ++q) {
                    U22 qq = { pk[2 * q], pk[2 * q + 1] };
                    *(u32x4*)&hl[(p * 4 + q) * 256 + 4 * l] =
                        __builtin_bit_cast(u32x4, qq);
                }
                // prefetch xp for t+4 (clamped tail; dummies unused)
                int tn = t + 4; if (tn > T_LEN - 1) tn = T_LEN - 1;
                const float* xpt = xpg + (size_t)tn * 2048;
#pragma unroll
                for (int m = 0; m < 8; ++m)
                    xb[p][m] = *(const f32x4*)(xpt + m * 256);
            }
            LDS_BARRIER();
        }
    } else {
        // ---- drain wave ----
        uint32_t* hgp = hg + ((size_t)g * T_LEN) * 1024 + 4 * l;
#pragma unroll 1
        for (int k = 0; k < T_LEN / 4; ++k) {
            if (k > 0) {
                const int c0 = k - 1;
                const uint32_t* hl = &hring[(c0 & 1) * 4096];
                u32x4 v[16];
#pragma unroll
                for (int i = 0; i < 16; ++i)
                    v[i] = *(const u32x4*)&hl[i * 256 + 4 * l];
                uint32_t* hp = hgp + (size_t)(4 * c0) * 1024;
#pragma unroll
                for (int sp = 0; sp < 4; ++sp)
#pragma unroll
                    for (int q = 0; q < 4; ++q)
                        *(u32x4*)(hp + sp * 1024 + q * 256) = v[sp * 4 + q];
            }
            LDS_BARRIER();   // lgkmcnt(0) drains our ds_reads before wave 0
                             // may overwrite this slot next chunk
        }
        // drain the final chunk (slot (1023)&1 == 1); last barrier above
        // guarantees wave 0's writes are visible.
        {
            const int c0 = T_LEN / 4 - 1;
            const uint32_t* hl = &hring[(c0 & 1) * 4096];
            u32x4 v[16];
#pragma unroll
            for (int i = 0; i < 16; ++i)
                v[i] = *(const u32x4*)&hl[i * 256 + 4 * l];
            uint32_t* hp = hgp + (size_t)(4 * c0) * 1024;
#pragma unroll
            for (int sp = 0; sp < 4; ++sp)
#pragma unroll
                for (int q = 0; q < 4; ++q)
                    *(u32x4*)(hp + sp * 1024 + q * 256) = v[sp * 4 + q];
        }
    }
}

// -------------------------------------------------------------------------
// Kernel 2: out[b,t,:] = relu(W2 . h_{t+1} + b2), K=16 MFMA.
// h fragments read verbatim (C-frag == B-frag for 16x16x16 under phiC).
// Grid 2048 = g*512 + tc, block 64, 8 t per block.
// -------------------------------------------------------------------------
__global__ __launch_bounds__(64, 2)
void out_kernel(const uint32_t* __restrict__ hg, const float* __restrict__ W2,
                const float* __restrict__ b2, float* __restrict__ out) {
    const int bid = blockIdx.x;
    const int g   = bid >> 9;
    const int tc  = bid & 511;
    const int l   = threadIdx.x;
    const int c   = l & 15, u = l >> 4;

    f16x4 wa[8][8];
#pragma unroll
    for (int m = 0; m < 8; ++m) {
        const float* wr = W2 + (16 * m + c) * 128 + 4 * u;
#pragma unroll
        for (int s = 0; s < 8; ++s)
            wa[m][s] = cvt_f16x4(*(const f32x4*)(wr + 16 * s));
    }
    f32x4 bi[8];
#pragma unroll
    for (int m = 0; m < 8; ++m) bi[m] = *(const f32x4*)(b2 + 16 * m + 4 * u);

    const int t0 = tc * 8;
    const uint32_t* hg0 = hg + ((size_t)g * T_LEN) * 1024 + 4 * l;
    float* op0 = out + (size_t)(16 * g + c) * T_LEN * NHID + 4 * u;
#pragma unroll 1
    for (int tt = 0; tt < 8; ++tt) {
        const int t = t0 + tt;
        const uint32_t* hp = hg0 + (size_t)t * 1024;
        f16x4 hb[8];
#pragma unroll
        for (int s = 0; s < 8; ++s)
            hb[s] = __builtin_bit_cast(f16x4,
                        *(const u32x2*)(hp + (s >> 1) * 256 + (s & 1) * 2));
        f32x4 acc[8];
#pragma unroll
        for (int m = 0; m < 8; ++m) {
            f32x4 a = bi[m];
#pragma unroll
            for (int s = 0; s < 8; ++s) a = MFMA16(wa[m][s], hb[s], a);
            acc[m] = relu4(a);
        }
        float* op = op0 + (size_t)t * NHID;
#pragma unroll
        for (int m = 0; m < 8; ++m) *(f32x4*)(op + 16 * m) = acc[m];
    }
}

// -------------------------------------------------------------------------
extern "C" void kernel_launch(void* const* d_in, const int* in_sizes, int n_in,
                              void* d_out, int out_size, void* d_ws, size_t ws_size,
                              hipStream_t stream) {
    const float* input = (const float*)d_in[0];  // (64, 4096, 128) f32
    const float* W1    = (const float*)d_in[1];  // (128, 256) f32
    const float* b1    = (const float*)d_in[2];  // (128,) f32
    const float* W2    = (const float*)d_in[3];  // (128, 128) f32
    const float* b2    = (const float*)d_in[4];  // (128,) f32
    float*    out = (float*)d_out;
    float*    xpb = (float*)d_out;               // xp scratch: full 128 MiB of
                                                 // d_out (f32), fully consumed
                                                 // by rec before out_kernel
                                                 // overwrites it
    uint32_t* hgb = (uint32_t*)d_ws;             // h stream: 64 MiB in d_ws

    xproj_kernel<<<1024, 64, 0, stream>>>(input, W1, b1, xpb);
    rec_kernel  <<<4,   128, 0, stream>>>(xpb, W1, hgb);
    out_kernel  <<<2048, 64, 0, stream>>>(hgb, W2, b2, out);
}